// Round 1
// baseline (1445.871 us; speedup 1.0000x reference)
//
#include <hip/hip_runtime.h>

// TrajectoryDecoder: fused persistent GRU decoder on MFMA 32x32x16 bf16.
// BK=49152 seqs, T=30, H=256. Block = 96 seqs, 512 thr (8 waves), grid 512.
// Each wave owns a 32-wide h-unit column slice; 3 gate accumulators (f32x16
// each); K=272 = 256 h + (x,y) folded for r/z gates + zero pad.
// h carried in fp32 registers (owning lane), bf16 copy in LDS for MFMA A.
// delta = h_new @ W_out^T reduced with DPP (VALU pipe), not ds_swizzle.

typedef __attribute__((ext_vector_type(8))) short short8;
typedef __bf16 bf16x8 __attribute__((ext_vector_type(8)));
typedef float f32x16 __attribute__((ext_vector_type(16)));
typedef float f32x4 __attribute__((ext_vector_type(4)));

#define HSTR 272          // Hb row stride (bf16 elems); 544B rows, 16B aligned
#define KS_HH 17          // 272 / 16
#define NSEQ_BLK 96
#define WHH_ELEMS (24 * 17 * 64 * 8)   // 208896
#define WH0_ELEMS (8 * 20 * 64 * 8)    // 81920

static __device__ __forceinline__ unsigned short f2bf(float f) {
  unsigned u = __builtin_bit_cast(unsigned, f);
  u += 0x7fffu + ((u >> 16) & 1u);          // RNE
  return (unsigned short)(u >> 16);
}
static __device__ __forceinline__ float bf2f(unsigned short h) {
  unsigned u = ((unsigned)h) << 16;
  return __builtin_bit_cast(float, u);
}
static __device__ __forceinline__ bf16x8 ldfrag(const unsigned short* p) {
  return __builtin_bit_cast(bf16x8, *(const short8*)p);
}
static __device__ __forceinline__ float fsig(float x) {
  return __builtin_amdgcn_rcpf(1.f + __builtin_amdgcn_exp2f(-1.44269504f * x));
}
static __device__ __forceinline__ float ftanh(float x) {
  // tanh(x) = 1 - 2/(1+e^{2x}); correct limits at +/-inf
  return 1.f - 2.f * __builtin_amdgcn_rcpf(1.f + __builtin_amdgcn_exp2f(2.88539008f * x));
}
// sum across each 16-lane row via DPP (VALU pipe, no LDS)
static __device__ __forceinline__ float dpp16sum(float x) {
  x += __builtin_bit_cast(float, __builtin_amdgcn_update_dpp(0, __builtin_bit_cast(int, x), 0xB1, 0xF, 0xF, true));  // quad_perm [1,0,3,2] : xor1
  x += __builtin_bit_cast(float, __builtin_amdgcn_update_dpp(0, __builtin_bit_cast(int, x), 0x4E, 0xF, 0xF, true));  // quad_perm [2,3,0,1] : xor2
  x += __builtin_bit_cast(float, __builtin_amdgcn_update_dpp(0, __builtin_bit_cast(int, x), 0x141, 0xF, 0xF, true)); // row_half_mirror : 4-blocks
  x += __builtin_bit_cast(float, __builtin_amdgcn_update_dpp(0, __builtin_bit_cast(int, x), 0x140, 0xF, 0xF, true)); // row_mirror : 8-blocks
  return x;
}

// ---------- prep: pack W_hh (+W_ih rows for r/z at k=256,257) into B-frag order ----------
// Whhp[nt 0..23][ks 0..16][lane 0..63][j 0..7], row = nt*32 + (lane&31),
// k = ks*16 + (lane>>5)*8 + j. B[k][n] = Wext[n][k].
__global__ void prep_whh_k(const float* __restrict__ Whh, const float* __restrict__ Wih,
                           unsigned short* __restrict__ Whhp) {
  int i = blockIdx.x * 256 + threadIdx.x;
  if (i >= WHH_ELEMS) return;
  int j = i & 7;
  int lane = (i >> 3) & 63;
  int rest = i >> 9;            // nt*17 + ks
  int ks = rest % 17;
  int nt = rest / 17;
  int row = nt * 32 + (lane & 31);     // 0..767 (r:0-255, z:256-511, n:512-767)
  int k = ks * 16 + ((lane >> 5) << 3) + j;
  float v = 0.f;
  if (k < 256) v = Whh[row * 256 + k];
  else if (k < 258 && row < 512) v = Wih[row * 2 + (k - 256)];  // fold x,y for r/z only
  Whhp[i] = f2bf(v);
}

// ---------- prep: pack W_h0 (256 x 290, K padded to 320) ----------
__global__ void prep_wh0_k(const float* __restrict__ Wh0, unsigned short* __restrict__ Wh0p) {
  int i = blockIdx.x * 256 + threadIdx.x;
  if (i >= WH0_ELEMS) return;
  int j = i & 7;
  int lane = (i >> 3) & 63;
  int rest = i >> 9;            // nt*20 + ks
  int ks = rest % 20;
  int nt = rest / 20;
  int row = nt * 32 + (lane & 31);     // 0..255
  int k = ks * 16 + ((lane >> 5) << 3) + j;
  float v = (k < 290) ? Wh0[row * 290 + k] : 0.f;
  Wh0p[i] = f2bf(v);
}

// ---------- prep: per-h-unit gate params [br, bz, bin, bhn, wn0, wn1, wo0, wo1] ----------
__global__ void prep_gp_k(const float* __restrict__ bih, const float* __restrict__ bhh,
                          const float* __restrict__ Wih, const float* __restrict__ Wout,
                          float* __restrict__ gpo) {
  int n = threadIdx.x;   // 256
  gpo[n * 8 + 0] = bih[n] + bhh[n];
  gpo[n * 8 + 1] = bih[n + 256] + bhh[n + 256];
  gpo[n * 8 + 2] = bih[n + 512];
  gpo[n * 8 + 3] = bhh[n + 512];
  gpo[n * 8 + 4] = Wih[(n + 512) * 2];
  gpo[n * 8 + 5] = Wih[(n + 512) * 2 + 1];
  gpo[n * 8 + 6] = Wout[n];
  gpo[n * 8 + 7] = Wout[256 + n];
}

// ---------- main fused GRU ----------
__global__ __launch_bounds__(512, 2) void gru_main_k(
    const float* __restrict__ ctx, const float* __restrict__ goals,
    const float* __restrict__ emb, const float* __restrict__ bh0,
    const float* __restrict__ bout,
    const unsigned short* __restrict__ Wh0p,
    const unsigned short* __restrict__ Whhp,
    const float* __restrict__ gp,
    float* __restrict__ out) {
  __shared__ unsigned short Hb[NSEQ_BLK * HSTR];        // 52224 B
  __shared__ float dpart[16 * NSEQ_BLK * 2];            // 12288 B: [w*2+half][s][c]
  __shared__ float posL[NSEQ_BLK * 2];                  // 768 B

  const int tid = threadIdx.x;
  const int w = tid >> 6;        // wave 0..7
  const int l = tid & 63;
  const int l31 = l & 31;
  const int grp = l >> 5;        // k-half / row-half selector
  const int seq0 = blockIdx.x * NSEQ_BLK;
  const int n0 = w * 32 + l31;   // this lane's h-unit column

  // ---------------- Phase 0: h0 = init_in @ W_h0^T + b_h0 ----------------
  f32x16 acc0[3];
  acc0[0] = f32x16{};
  acc0[1] = f32x16{};
  acc0[2] = f32x16{};
  unsigned short* As = Hb;       // overlay staging, stride 176 (352B rows)
  for (int c = 0; c < 2; ++c) {  // two K-chunks of 160
    for (int i = tid; i < NSEQ_BLK * 160; i += 512) {
      int row = i / 160;
      int col = i - row * 160;
      int d = c * 160 + col;
      int s = seq0 + row;
      int b = s / 6;
      float v;
      if (d < 256)      v = ctx[b * 256 + d];
      else if (d < 258) v = goals[s * 2 + (d - 256)];
      else if (d < 290) v = emb[b * 32 + (d - 258)];
      else              v = 0.f;
      As[row * 176 + col] = f2bf(v);
    }
    __syncthreads();
    for (int ks = 0; ks < 10; ++ks) {
      bf16x8 bf = ldfrag(&Wh0p[((w * 20 + c * 10 + ks) * 64 + l) * 8]);
#pragma unroll
      for (int mc = 0; mc < 3; ++mc) {
        bf16x8 af = ldfrag(&As[(mc * 32 + l31) * 176 + ks * 16 + grp * 8]);
        acc0[mc] = __builtin_amdgcn_mfma_f32_32x32x16_bf16(af, bf, acc0[mc], 0, 0, 0);
      }
    }
    __syncthreads();
  }
  // epilogue: + b_h0, keep fp32 h in regs, bf16 copy into Hb (stride 272)
  float hreg[3][16];
  {
    float b0 = bh0[n0];
#pragma unroll
    for (int mc = 0; mc < 3; ++mc)
#pragma unroll
      for (int r = 0; r < 16; ++r) {
        int row = (r & 3) + 8 * (r >> 2) + 4 * grp;   // C/D layout [m74/m101]
        int s = mc * 32 + row;
        float h = acc0[mc][r] + b0;
        hreg[mc][r] = h;
        Hb[s * HSTR + n0] = f2bf(h);
      }
  }
  // zero x,y (cols 256,257) + K-pad cols 258..271; zero pos
  for (int i = tid; i < NSEQ_BLK * 16; i += 512) {
    int s = i >> 4, c = i & 15;
    Hb[s * HSTR + 256 + c] = 0;
  }
  if (tid < 192) posL[tid] = 0.f;
  __syncthreads();

  // hoisted per-lane gate params for column n0
  float brr, bzz, bin_, bhn, wn0, wn1, wo0, wo1;
  {
    f32x4 g0 = *(const f32x4*)&gp[n0 * 8];
    f32x4 g1 = *(const f32x4*)&gp[n0 * 8 + 4];
    brr = g0[0]; bzz = g0[1]; bin_ = g0[2]; bhn = g0[3];
    wn0 = g1[0]; wn1 = g1[1]; wo0 = g1[2]; wo1 = g1[3];
  }
  const float bo0 = bout[0], bo1 = bout[1];

  const unsigned short* wr = &Whhp[((w)*17 * 64 + l) * 8];
  const unsigned short* wzp = &Whhp[((8 + w) * 17 * 64 + l) * 8];
  const unsigned short* wnp = &Whhp[((16 + w) * 17 * 64 + l) * 8];

  // ---------------- T recurrent steps ----------------
  for (int t = 0; t < 30; ++t) {
    // Phase A: gh(+gi for r,z) = [h|x,y] @ Wext^T  over K=272
    f32x16 ar[3], az[3], an[3];
#pragma unroll
    for (int mc = 0; mc < 3; ++mc) { ar[mc] = f32x16{}; az[mc] = f32x16{}; an[mc] = f32x16{}; }
    for (int ks = 0; ks < KS_HH; ++ks) {
      bf16x8 br_ = ldfrag(wr + ks * 512);
      bf16x8 bz_ = ldfrag(wzp + ks * 512);
      bf16x8 bn_ = ldfrag(wnp + ks * 512);
#pragma unroll
      for (int mc = 0; mc < 3; ++mc) {
        bf16x8 af = ldfrag(&Hb[(mc * 32 + l31) * HSTR + ks * 16 + grp * 8]);
        ar[mc] = __builtin_amdgcn_mfma_f32_32x32x16_bf16(af, br_, ar[mc], 0, 0, 0);
        az[mc] = __builtin_amdgcn_mfma_f32_32x32x16_bf16(af, bz_, az[mc], 0, 0, 0);
        an[mc] = __builtin_amdgcn_mfma_f32_32x32x16_bf16(af, bn_, an[mc], 0, 0, 0);
      }
    }
    __syncthreads();   // all reads of Hb done before h_new writes

    // Phase B: gates + h update + delta partial (DPP reduce over 16 cols)
#pragma unroll
    for (int mc = 0; mc < 3; ++mc) {
#pragma unroll
      for (int r = 0; r < 16; ++r) {
        int row = (r & 3) + 8 * (r >> 2) + 4 * grp;
        int s = mc * 32 + row;
        unsigned xy = *(const unsigned*)&Hb[s * HSTR + 256];   // bf16 x,y pair
        float x = bf2f((unsigned short)(xy & 0xffffu));
        float y = bf2f((unsigned short)(xy >> 16));
        float rg = fsig(ar[mc][r] + brr);
        float zg = fsig(az[mc][r] + bzz);
        float ing = fmaf(x, wn0, fmaf(y, wn1, bin_));
        float ng = ftanh(fmaf(rg, an[mc][r] + bhn, ing));
        float h = hreg[mc][r];
        float hnew = fmaf(zg, h - ng, ng);    // (1-z)*n + z*h
        hreg[mc][r] = hnew;
        Hb[s * HSTR + n0] = f2bf(hnew);
        float dx = dpp16sum(hnew * wo0);
        float dy = dpp16sum(hnew * wo1);
        if ((l & 15) == 0) {
          int half = (l >> 4) & 1;
          int base = (((w * 2 + half) * NSEQ_BLK) + s) * 2;
          dpart[base] = dx;
          dpart[base + 1] = dy;
        }
      }
    }
    __syncthreads();

    // Phase C: pos += delta + b_out; emit raw pred; refresh bf16 x,y
    if (tid < 192) {
      int s = tid >> 1, c = tid & 1;
      float d = (c == 0) ? bo0 : bo1;
#pragma unroll
      for (int q = 0; q < 16; ++q) d += dpart[(q * NSEQ_BLK + s) * 2 + c];
      float p = posL[tid] + d;
      posL[tid] = p;
      out[((seq0 + s) * 30 + t) * 2 + c] = p;
      Hb[s * HSTR + 256 + c] = f2bf(p);
    }
    __syncthreads();
  }
}

// ---------- correction: out = pred + (goal - pred_T) * (t+1)/30, in place ----------
__global__ void corr_k(float* __restrict__ out, const float* __restrict__ goals) {
  __shared__ float buf[240];
  int tid = threadIdx.x;
  int s0 = blockIdx.x * 4;              // 4 seqs per block
  float v = 0.f;
  if (tid < 240) { v = out[s0 * 60 + tid]; buf[tid] = v; }
  __syncthreads();
  if (tid < 240) {
    int sl = tid / 60;
    int rem = tid - sl * 60;
    int t = rem >> 1, c = rem & 1;
    float pT = buf[sl * 60 + 58 + c];
    float g = goals[(s0 + sl) * 2 + c];
    out[s0 * 60 + tid] = v + (g - pT) * ((float)(t + 1) * (1.f / 30.f));
  }
}

extern "C" void kernel_launch(void* const* d_in, const int* in_sizes, int n_in,
                              void* d_out, int out_size, void* d_ws, size_t ws_size,
                              hipStream_t stream) {
  (void)in_sizes; (void)n_in; (void)out_size; (void)ws_size;
  const float* ctx  = (const float*)d_in[0];
  const float* goals= (const float*)d_in[1];
  const float* emb  = (const float*)d_in[2];
  const float* Wh0  = (const float*)d_in[3];
  const float* bh0  = (const float*)d_in[4];
  const float* Wih  = (const float*)d_in[5];
  const float* Whh  = (const float*)d_in[6];
  const float* bih  = (const float*)d_in[7];
  const float* bhh  = (const float*)d_in[8];
  const float* Wout = (const float*)d_in[9];
  const float* bout = (const float*)d_in[10];
  float* out = (float*)d_out;

  unsigned short* Whhp = (unsigned short*)d_ws;                          // 417792 B
  unsigned short* Wh0p = (unsigned short*)((char*)d_ws + 417792);        // 163840 B
  float* gpo = (float*)((char*)d_ws + 417792 + 163840);                  // 8192 B

  hipLaunchKernelGGL(prep_whh_k, dim3(816), dim3(256), 0, stream, Whh, Wih, Whhp);
  hipLaunchKernelGGL(prep_wh0_k, dim3(320), dim3(256), 0, stream, Wh0, Wh0p);
  hipLaunchKernelGGL(prep_gp_k, dim3(1), dim3(256), 0, stream, bih, bhh, Wih, Wout, gpo);
  hipLaunchKernelGGL(gru_main_k, dim3(512), dim3(512), 0, stream,
                     ctx, goals, emb, bh0, bout, Wh0p, Whhp, gpo, out);
  hipLaunchKernelGGL(corr_k, dim3(12288), dim3(256), 0, stream, out, goals);
}